// Round 1
// baseline (1003.058 us; speedup 1.0000x reference)
//
#include <hip/hip_runtime.h>

// Problem constants (reference: N=32768, M=8192, D=64, fp32)
#define N_ROWS 32768
#define M_COLS 8192
#define D_DIM  64
#define JC     8      // j-chunks (grid.y) -> partial mins
#define TJ     128    // y rows staged per LDS tile (128*64*4B = 32 KB)
#define BLOCK  256
#define ROWS_PER_BLOCK 512  // 2 rows per thread

// ---------- kernel 1: t[j] = ||y_j||^2 - psi[j] ----------
__global__ void prep_t_kernel(const float* __restrict__ y,
                              const float* __restrict__ psi,
                              float* __restrict__ t) {
    int j = blockIdx.x * blockDim.x + threadIdx.x;
    if (j >= M_COLS) return;
    const float4* yr = reinterpret_cast<const float4*>(y + (size_t)j * D_DIM);
    float s = 0.f;
#pragma unroll
    for (int k = 0; k < D_DIM / 4; ++k) {
        float4 v = yr[k];
        s += v.x * v.x + v.y * v.y + v.z * v.z + v.w * v.w;
    }
    t[j] = s - psi[j];
}

// ---------- kernel 2: partial min over a j-chunk ----------
// part[jc*N + i] = x2[i] + min_{j in chunk} (t[j] - 2*<x_i, y_j>)
__global__ __launch_bounds__(BLOCK) void partial_min_kernel(
    const float* __restrict__ x, const float* __restrict__ y,
    const float* __restrict__ t, float* __restrict__ part) {
    __shared__ float4 sY[TJ * (D_DIM / 4)];
    __shared__ float  sT[TJ];

    const int tid = threadIdx.x;
    const int rb  = blockIdx.x;   // row block [0,64)
    const int jc  = blockIdx.y;   // j chunk  [0,JC)

    const int i0 = rb * ROWS_PER_BLOCK + tid;
    const int i1 = i0 + BLOCK;

    // load 2 x-rows into registers, compute ||x||^2 on the fly
    float4 xr0[D_DIM / 4], xr1[D_DIM / 4];
    const float4* p0 = reinterpret_cast<const float4*>(x + (size_t)i0 * D_DIM);
    const float4* p1 = reinterpret_cast<const float4*>(x + (size_t)i1 * D_DIM);
    float x20 = 0.f, x21 = 0.f;
#pragma unroll
    for (int k = 0; k < D_DIM / 4; ++k) {
        xr0[k] = p0[k];
        xr1[k] = p1[k];
        x20 += xr0[k].x * xr0[k].x + xr0[k].y * xr0[k].y +
               xr0[k].z * xr0[k].z + xr0[k].w * xr0[k].w;
        x21 += xr1[k].x * xr1[k].x + xr1[k].y * xr1[k].y +
               xr1[k].z * xr1[k].z + xr1[k].w * xr1[k].w;
    }

    float m0 = INFINITY, m1 = INFINITY;
    const int jbase  = jc * (M_COLS / JC);
    const int ntiles = (M_COLS / JC) / TJ;  // 1024/128 = 8

    for (int tile = 0; tile < ntiles; ++tile) {
        const int jt = jbase + tile * TJ;
        __syncthreads();  // protect previous tile from overwrite
        // stage y tile: 2048 float4, 256 threads -> 8 each, coalesced
        const float4* ysrc = reinterpret_cast<const float4*>(y + (size_t)jt * D_DIM);
#pragma unroll
        for (int k = 0; k < (TJ * D_DIM / 4) / BLOCK; ++k)
            sY[tid + k * BLOCK] = ysrc[tid + k * BLOCK];
        if (tid < TJ) sT[tid] = t[jt + tid];
        __syncthreads();

        for (int jj = 0; jj < TJ; ++jj) {
            float a0 = 0.f, a1 = 0.f;
#pragma unroll
            for (int k = 0; k < D_DIM / 4; ++k) {
                float4 yv = sY[jj * (D_DIM / 4) + k];  // wave-broadcast read
                a0 += xr0[k].x * yv.x + xr0[k].y * yv.y +
                      xr0[k].z * yv.z + xr0[k].w * yv.w;
                a1 += xr1[k].x * yv.x + xr1[k].y * yv.y +
                      xr1[k].z * yv.z + xr1[k].w * yv.w;
            }
            const float tv = sT[jj];
            m0 = fminf(m0, tv - 2.f * a0);
            m1 = fminf(m1, tv - 2.f * a1);
        }
    }
    part[(size_t)jc * N_ROWS + i0] = m0 + x20;
    part[(size_t)jc * N_ROWS + i1] = m1 + x21;
}

// ---------- kernel 3: per-row min over chunks, partial row-sum per block ----------
__global__ __launch_bounds__(BLOCK) void row_reduce_kernel(
    const float* __restrict__ part, float* __restrict__ bsum) {
    const int tid = threadIdx.x;
    float s = 0.f;
#pragma unroll
    for (int r = 0; r < 2; ++r) {
        const int i = blockIdx.x * 512 + r * 256 + tid;
        float m = part[i];
#pragma unroll
        for (int c = 1; c < JC; ++c)
            m = fminf(m, part[(size_t)c * N_ROWS + i]);
        s += m;
    }
    // wave reduce (64 lanes)
    for (int off = 32; off > 0; off >>= 1) s += __shfl_down(s, off, 64);
    __shared__ float tmp[4];
    const int lane = tid & 63, wave = tid >> 6;
    if (lane == 0) tmp[wave] = s;
    __syncthreads();
    if (tid == 0) bsum[blockIdx.x] = tmp[0] + tmp[1] + tmp[2] + tmp[3];
}

// ---------- kernel 4: final scalar ----------
__global__ __launch_bounds__(BLOCK) void final_kernel(
    const float* __restrict__ bsum, const float* __restrict__ psi,
    float* __restrict__ out) {
    const int tid = threadIdx.x;
    float s = (tid < 64) ? bsum[tid] : 0.f;
    float p = 0.f;
    for (int j = tid; j < M_COLS; j += BLOCK) p += psi[j];
    for (int off = 32; off > 0; off >>= 1) {
        s += __shfl_down(s, off, 64);
        p += __shfl_down(p, off, 64);
    }
    __shared__ float ts[4], tp[4];
    const int lane = tid & 63, wave = tid >> 6;
    if (lane == 0) { ts[wave] = s; tp[wave] = p; }
    __syncthreads();
    if (tid == 0) {
        float S = ts[0] + ts[1] + ts[2] + ts[3];
        float P = tp[0] + tp[1] + tp[2] + tp[3];
        out[0] = S / (float)N_ROWS + P / (float)M_COLS;
    }
}

extern "C" void kernel_launch(void* const* d_in, const int* in_sizes, int n_in,
                              void* d_out, int out_size, void* d_ws, size_t ws_size,
                              hipStream_t stream) {
    const float* x   = (const float*)d_in[0];   // [N,D]
    const float* y   = (const float*)d_in[1];   // [M,D]
    const float* psi = (const float*)d_in[2];   // [M]
    float* out = (float*)d_out;

    // workspace layout
    float* part = (float*)d_ws;                          // JC*N floats = 1 MB
    float* t    = part + (size_t)JC * N_ROWS;            // M floats
    float* bsum = t + M_COLS;                            // 64 floats

    prep_t_kernel<<<M_COLS / BLOCK, BLOCK, 0, stream>>>(y, psi, t);
    partial_min_kernel<<<dim3(N_ROWS / ROWS_PER_BLOCK, JC), BLOCK, 0, stream>>>(x, y, t, part);
    row_reduce_kernel<<<N_ROWS / 512, BLOCK, 0, stream>>>(part, bsum);
    final_kernel<<<1, BLOCK, 0, stream>>>(bsum, psi, out);
}